// Round 2
// baseline (387.438 us; speedup 1.0000x reference)
//
#include <hip/hip_runtime.h>
#include <cmath>

#define DIM 512
#define NB 4
#define SEQ 4096

typedef __bf16 bf16;
typedef __bf16 bf16x8 __attribute__((ext_vector_type(8)));
typedef float  f32x4  __attribute__((ext_vector_type(4)));

__device__ __forceinline__ float fast_sig(float x) { return 1.f / (1.f + __expf(-x)); }
__device__ __forceinline__ float fast_tanh(float x) {
  float cx = fminf(fmaxf(x, -15.f), 15.f);
  float e = __expf(2.f * cx);
  return (e - 1.f) / (e + 1.f);
}
__device__ __forceinline__ bf16x8 ld8f(const float* p) {
  float4 u = *(const float4*)p, v = *(const float4*)(p + 4);
  return (bf16x8){(bf16)u.x, (bf16)u.y, (bf16)u.z, (bf16)u.w,
                  (bf16)v.x, (bf16)v.y, (bf16)v.z, (bf16)v.w};
}

// ---------------- r-scan: 3-pass exact chunked scan ----------------
constexpr int SC = 64, NSC = SEQ / SC;

__global__ __launch_bounds__(256) void scan_chunk(const float* __restrict__ K,
                                                  const float* __restrict__ V,
                                                  const float* __restrict__ decay,
                                                  float* __restrict__ R,
                                                  float* __restrict__ E) {
  int idx = blockIdx.x * 256 + threadIdx.x;     // NB*NSC*DIM = 131072
  int d = idx & (DIM - 1);
  int c = (idx >> 9) & (NSC - 1);
  int b = idx >> 15;
  float dec = decay[d >> 6];
  size_t base = ((size_t)b * SEQ + (size_t)c * SC) * DIM + d;
  float r = 0.f;
  #pragma unroll 4
  for (int i = 0; i < SC; ++i) {
    size_t o = base + (size_t)i * DIM;
    r = dec * r + K[o] * V[o];
    R[o] = r;
  }
  E[((size_t)b * NSC + c) * DIM + d] = r;
}

__global__ __launch_bounds__(256) void scan_carry(const float* __restrict__ E,
                                                  const float* __restrict__ decay,
                                                  float* __restrict__ P) {
  int idx = blockIdx.x * 256 + threadIdx.x;     // 2048
  int d = idx & (DIM - 1);
  int b = idx >> 9;
  float dec = decay[d >> 6];
  float lam = powf(dec, (float)SC);
  float pv = 0.f;
  for (int c = 0; c < NSC; ++c) {
    size_t o = ((size_t)b * NSC + c) * DIM + d;
    P[o] = pv;
    pv = E[o] + lam * pv;
  }
}

__global__ __launch_bounds__(256) void scan_fix_b(const float* __restrict__ decay,
                                                  const float* __restrict__ P,
                                                  const float* __restrict__ R,
                                                  bf16* __restrict__ Rb) {
  int idx = blockIdx.x * 256 + threadIdx.x;
  int d = idx & (DIM - 1);
  int c = (idx >> 9) & (NSC - 1);
  int b = idx >> 15;
  float pv = P[((size_t)b * NSC + c) * DIM + d];
  float dec = decay[d >> 6];
  size_t base = ((size_t)b * SEQ + (size_t)c * SC) * DIM + d;
  float wgt = dec;
  #pragma unroll 4
  for (int i = 0; i < SC; ++i) {
    size_t o = base + (size_t)i * DIM;
    Rb[o] = (bf16)(R[o] + wgt * pv);
    wgt *= dec;
  }
}

// ---------------- weight conversion: 4 x (512x512) fp32 -> bf16 ----------------
__global__ __launch_bounds__(256) void convert_w(const float* __restrict__ a,
                                                 const float* __restrict__ b,
                                                 const float* __restrict__ c,
                                                 const float* __restrict__ d,
                                                 bf16* __restrict__ o4) {
  int gid = blockIdx.x * 256 + threadIdx.x;     // 262144 threads, 4 elems each
  int m = gid >> 16;
  int off = (gid & 65535) << 2;
  const float* srcs[4] = {a, b, c, d};
  float4 v = *(const float4*)(srcs[m] + off);
  bf16* o = o4 + (size_t)m * 262144 + off;
  o[0] = (bf16)v.x; o[1] = (bf16)v.y; o[2] = (bf16)v.z; o[3] = (bf16)v.w;
}

// ---------------- MFMA GEMM, 128x128 tile: Out = X @ W^T ----------------
// MODE 0 (gate): X = q (fp32, converted in staging); g = sigmoid(z+gb);
//                Gout = g (bf16), Pout = (1-g)*q (bf16)
// MODE 1 (D):    z = Pb@Ab^T + Rb@Bmb^T (virtual K=1024); Bout = z (bf16)
// MODE 2 (out):  z = Sb@owb^T + ob;  Fout = z (fp32)
// 256 thr = 4 waves, each owns a 64x64 quadrant (4x4 grid of 16x16x32 MFMA).
// LDS rows padded to 72 bf16. Staging: each thread loads/stores 4 bf16x8 per
// matrix per k-tile (rows srow+32j), covering all 128 rows.
template <int MODE>
__global__ __launch_bounds__(256) void gemm_mfma(
    const float* __restrict__ Xf,
    const bf16* __restrict__ Xa, const bf16* __restrict__ Xc,
    const bf16* __restrict__ Wa, const bf16* __restrict__ Wb,
    const float* __restrict__ bias,
    float* __restrict__ Fout, bf16* __restrict__ Bout,
    bf16* __restrict__ Gout, bf16* __restrict__ Pout) {
  __shared__ __align__(16) bf16 Xs[128][72];
  __shared__ __align__(16) bf16 Ws[128][72];
  const int tid = threadIdx.x;
  const int wave = tid >> 6, lane = tid & 63;
  const int quad = lane >> 4, l16 = lane & 15;
  const int wm = wave & 1, wn = wave >> 1;
  const int m0 = blockIdx.x * 128, n0 = blockIdx.y * 128;
  const int srow = tid >> 3;            // 0..31 (rows srow+32j, j=0..3)
  const int scol = (tid & 7) * 8;       // 0..56

  const int KTOT = (MODE == 1) ? 2 * DIM : DIM;

  auto ldX = [&](int row, int k) -> bf16x8 {
    if constexpr (MODE == 0) {
      return ld8f(Xf + (size_t)row * DIM + k);
    } else if constexpr (MODE == 1) {
      const bf16* X = (k >= DIM) ? Xc : Xa;
      return *(const bf16x8*)(X + (size_t)row * DIM + (k & (DIM - 1)));
    } else {
      return *(const bf16x8*)(Xa + (size_t)row * DIM + k);
    }
  };
  auto ldW = [&](int row, int k) -> bf16x8 {
    const bf16* W = (MODE == 1 && k >= DIM) ? Wb : Wa;
    return *(const bf16x8*)(W + (size_t)row * DIM + (k & (DIM - 1)));
  };

  f32x4 acc[4][4] = {};
  bf16x8 px[4], pw[4];
  #pragma unroll
  for (int j = 0; j < 4; ++j) {
    px[j] = ldX(m0 + srow + 32 * j, scol);
    pw[j] = ldW(n0 + srow + 32 * j, scol);
  }

  for (int k0 = 0; k0 < KTOT; k0 += 64) {
    if (k0) __syncthreads();
    #pragma unroll
    for (int j = 0; j < 4; ++j) {
      *(bf16x8*)&Xs[srow + 32 * j][scol] = px[j];
      *(bf16x8*)&Ws[srow + 32 * j][scol] = pw[j];
    }
    if (k0 + 64 < KTOT) {
      #pragma unroll
      for (int j = 0; j < 4; ++j) {
        px[j] = ldX(m0 + srow + 32 * j, k0 + 64 + scol);
        pw[j] = ldW(n0 + srow + 32 * j, k0 + 64 + scol);
      }
    }
    __syncthreads();
    #pragma unroll
    for (int ks = 0; ks < 2; ++ks) {
      const int kk = ks * 32 + quad * 8;
      bf16x8 af[4], bfr[4];
      #pragma unroll
      for (int i = 0; i < 4; ++i) af[i]  = *(const bf16x8*)&Xs[wm * 64 + i * 16 + l16][kk];
      #pragma unroll
      for (int j = 0; j < 4; ++j) bfr[j] = *(const bf16x8*)&Ws[wn * 64 + j * 16 + l16][kk];
      #pragma unroll
      for (int i = 0; i < 4; ++i)
        #pragma unroll
        for (int j = 0; j < 4; ++j)
          acc[i][j] = __builtin_amdgcn_mfma_f32_16x16x32_bf16(af[i], bfr[j], acc[i][j], 0, 0, 0);
    }
  }

  #pragma unroll
  for (int i = 0; i < 4; ++i)
    #pragma unroll
    for (int j = 0; j < 4; ++j)
      #pragma unroll
      for (int r = 0; r < 4; ++r) {
        const int row = m0 + wm * 64 + i * 16 + quad * 4 + r;
        const int col = n0 + wn * 64 + j * 16 + l16;
        const size_t o = (size_t)row * DIM + col;
        const float z = acc[i][j][r];
        if constexpr (MODE == 0) {
          float g = fast_sig(z + bias[col]);
          Gout[o] = (bf16)g;
          Pout[o] = (bf16)((1.f - g) * Xf[o]);
        } else if constexpr (MODE == 1) {
          Bout[o] = (bf16)z;
        } else {
          Fout[o] = z + bias[col];
        }
      }
}

// ---------------- sequential core via MFMA ----------------
// 4096 streams (CC=4), 16 per WG -> 256 WGs (1 per CU). TT = 10 steps
// (WU=6 warmup + warm-start u0 = g_t0 * tanh(D_{t0-1}); initial s-err ~0.12
// rms contracts <=0.38/step -> residual ~3.6e-4 after 6 steps, well under the
// bf16 quantum of s (~4e-3)).
// A is STEP-INVARIANT: k-tiles 0..NLT-1 live in LDS; NLT..15 stream from L2
// via a 4-slot register ring primed at step start.
// The per-step barrier only needs LDS visibility, so we use raw
// "s_waitcnt lgkmcnt(0); s_barrier" — in-flight loads/stores legally cross it.
// D/G loads are SOFTWARE-PIPELINED ONE STEP AHEAD: step p issues the loads for
// step p+1 before p's epilogue/barrier, so each HBM load gets a full step
// (~thousands of cycles) of cover instead of racing the same-step MFMA
// section. Previously the whole 16-wave lockstep WG stalled on same-step HBM
// latency every step (measured: ~18k of 25k cycles/step idle).
constexpr int CC = 4, WU = 6, TT = CC + WU;
constexpr int NSTR = 16;
constexpr int USTR = 520;       // 1040 B row stride: 2-way bank alias (free)
constexpr int NLT = 3;          // LDS-resident A k-tiles per wave (96 KB/WG)

__global__ __launch_bounds__(1024, 4) void seq_mfma(const bf16* __restrict__ Ab,
                                                    const bf16* __restrict__ Gb,
                                                    const bf16* __restrict__ Db,
                                                    bf16* __restrict__ Sb) {
  __shared__ __align__(16) bf16 U[2][NSTR * USTR];        // 33,280 B
  __shared__ __align__(16) bf16 Alds[16 * NLT * 2 * 64 * 8]; // 98,304 B
  const int tid = threadIdx.x;
  const int wave = tid >> 6, lane = tid & 63;
  const int quad = lane >> 4, l16 = lane & 15;
  const int n0 = wave * 32;                      // 16 waves cover 512 cols
  const int b = blockIdx.x >> 6;                 // 64 WGs per batch
  const int cbase = (blockIdx.x & 63) * NSTR;    // 1024 chunks per batch
  const size_t base = (size_t)b * SEQ * DIM;

  const bf16* arow0 = Ab + (size_t)(n0 + l16) * DIM + quad * 8;
  const bf16* arow1 = arow0 + (size_t)16 * DIM;

  // stage this wave's first NLT A k-tiles into LDS (wave-private)
  bf16x8* Af = (bf16x8*)Alds;
  #pragma unroll
  for (int kt = 0; kt < NLT; ++kt) {
    Af[((wave * NLT + kt) * 2 + 0) * 64 + lane] = *(const bf16x8*)(arow0 + kt * 32);
    Af[((wave * NLT + kt) * 2 + 1) * 64 + lane] = *(const bf16x8*)(arow1 + kt * 32);
  }

  // D/G loader for step p (masked against sequence bounds)
  auto loadDG = [&](int p, float dv[2][4], float gv[2][4]) {
    #pragma unroll
    for (int tn = 0; tn < 2; ++tn)
      #pragma unroll
      for (int r = 0; r < 4; ++r) {
        const int strm = quad * 4 + r;
        const int t = (cbase + strm) * CC + p - WU;
        const int col = n0 + tn * 16 + l16;
        dv[tn][r] = (t >= 0 && t < SEQ)
                        ? (float)Db[base + (size_t)t * DIM + col] : 0.f;
        gv[tn][r] = (t + 1 >= 0 && t + 1 < SEQ)
                        ? (float)Gb[base + (size_t)(t + 1) * DIM + col] : 0.f;
      }
  };

  // warm-start: u = g_{t0} * tanh(D_{t0-1})  (zero where indices < 0)
  #pragma unroll
  for (int tn = 0; tn < 2; ++tn)
    #pragma unroll
    for (int r = 0; r < 4; ++r) {
      const int strm = quad * 4 + r;
      const int t0 = (cbase + strm) * CC - WU;
      const int col = n0 + tn * 16 + l16;
      float s0 = (t0 - 1 >= 0) ? fast_tanh((float)Db[base + (size_t)(t0 - 1) * DIM + col]) : 0.f;
      float g0 = (t0 >= 0) ? (float)Gb[base + (size_t)t0 * DIM + col] : 0.f;
      U[0][strm * USTR + col] = (bf16)(g0 * s0);
    }

  // pipeline prologue: D/G for step 0
  float dvc[2][4], gvc[2][4], dvn[2][4], gvn[2][4];
  loadDG(0, dvc, gvc);
  __syncthreads();

  int cur = 0;
  for (int p = 0; p < TT; ++p) {
    // prime streamed-A ring FIRST so the L2 loads issue earliest
    bf16x8 pb0[4], pb1[4];
    #pragma unroll
    for (int i = 0; i < 4; ++i) {
      pb0[i] = *(const bf16x8*)(arow0 + (NLT + i) * 32);
      pb1[i] = *(const bf16x8*)(arow1 + (NLT + i) * 32);
    }

    // cross-step prefetch: D/G for step p+1 (consumed after next barrier;
    // these stay vmcnt-outstanding across the LDS-only barrier)
    loadDG(p + 1, dvn, gvn);

    f32x4 acc0 = {}, acc1 = {};
    const bf16* u0 = &U[cur][l16 * USTR + quad * 8];
    // LDS-resident tiles first (hides the ring's first-load latency)
    #pragma unroll
    for (int kt = 0; kt < NLT; ++kt) {
      bf16x8 av = *(const bf16x8*)(u0 + kt * 32);
      bf16x8 b0 = Af[((wave * NLT + kt) * 2 + 0) * 64 + lane];
      bf16x8 b1 = Af[((wave * NLT + kt) * 2 + 1) * 64 + lane];
      acc0 = __builtin_amdgcn_mfma_f32_16x16x32_bf16(av, b0, acc0, 0, 0, 0);
      acc1 = __builtin_amdgcn_mfma_f32_16x16x32_bf16(av, b1, acc1, 0, 0, 0);
    }
    // streamed tiles (L2), 4-slot ring
    #pragma unroll
    for (int kt = NLT; kt < 16; ++kt) {
      bf16x8 av = *(const bf16x8*)(u0 + kt * 32);
      const int slot = (kt - NLT) & 3;
      bf16x8 b0 = pb0[slot], b1 = pb1[slot];
      if (kt + 4 < 16) {
        pb0[slot] = *(const bf16x8*)(arow0 + (kt + 4) * 32);
        pb1[slot] = *(const bf16x8*)(arow1 + (kt + 4) * 32);
      }
      acc0 = __builtin_amdgcn_mfma_f32_16x16x32_bf16(av, b0, acc0, 0, 0, 0);
      acc1 = __builtin_amdgcn_mfma_f32_16x16x32_bf16(av, b1, acc1, 0, 0, 0);
    }

    const int nxt = cur ^ 1;
    #pragma unroll
    for (int tn = 0; tn < 2; ++tn)
      #pragma unroll
      for (int r = 0; r < 4; ++r) {
        const int strm = quad * 4 + r;
        const int t = (cbase + strm) * CC + p - WU;
        const int col = n0 + tn * 16 + l16;
        const float z = (tn ? acc1[r] : acc0[r]) + dvc[tn][r];
        const float s = fast_tanh(z);
        if (p >= WU) Sb[base + (size_t)t * DIM + col] = (bf16)s;
        U[nxt][strm * USTR + col] = (bf16)(gvc[tn][r] * s);
      }
    // LDS-only barrier: U writes must be visible; A loads / S stores / next-
    // step D/G loads may legally remain in flight.
    asm volatile("s_waitcnt lgkmcnt(0)\n\ts_barrier" ::: "memory");
    cur = nxt;
    #pragma unroll
    for (int tn = 0; tn < 2; ++tn)
      #pragma unroll
      for (int r = 0; r < 4; ++r) {
        dvc[tn][r] = dvn[tn][r];
        gvc[tn][r] = gvn[tn][r];
      }
  }
}

// ---------------- launch ----------------
extern "C" void kernel_launch(void* const* d_in, const int* in_sizes, int n_in,
                              void* d_out, int out_size, void* d_ws, size_t ws_size,
                              hipStream_t stream) {
  const float* q     = (const float*)d_in[0];
  const float* k     = (const float*)d_in[1];
  const float* v     = (const float*)d_in[2];
  const float* A     = (const float*)d_in[3];
  const float* Bm    = (const float*)d_in[4];
  const float* gw    = (const float*)d_in[5];
  const float* gb    = (const float*)d_in[6];
  const float* ow    = (const float*)d_in[7];
  const float* ob    = (const float*)d_in[8];
  const float* decay = (const float*)d_in[9];
  float* out = (float*)d_out;

  const size_t NE = (size_t)NB * SEQ * DIM;       // 8,388,608
  char* w = (char*)d_ws;
  float* Rf  = (float*)w;  w += NE * 4;           // fp32 r (scan); reused as bf16 D
  float* Eb  = (float*)w;  w += (size_t)NB * NSC * DIM * 4;
  float* Pc  = (float*)w;  w += (size_t)NB * NSC * DIM * 4;
  bf16*  Gbuf= (bf16*)w;   w += NE * 2;
  bf16*  Pb  = (bf16*)w;   w += NE * 2;
  bf16*  Rb  = (bf16*)w;   w += NE * 2;           // bf16 r; reused as S
  bf16*  W4  = (bf16*)w;   w += 4 * 262144 * 2;   // ~83 MB total
  bf16 *gwb = W4, *Ab = W4 + 262144, *Bmb = W4 + 2 * 262144, *owb = W4 + 3 * 262144;
  bf16*  Db = (bf16*)Rf;                          // bf16 D overwrites dead fp32 r
  bf16*  Sb = Rb;

  // 1) exact chunked linear scan for r (fp32), emit bf16
  scan_chunk<<<512, 256, 0, stream>>>(k, v, decay, Rf, Eb);
  scan_carry<<<8, 256, 0, stream>>>(Eb, decay, Pc);
  scan_fix_b<<<512, 256, 0, stream>>>(decay, Pc, Rf, Rb);
  convert_w<<<1024, 256, 0, stream>>>(gw, A, Bm, ow, W4);

  dim3 gg(16384 / 128, DIM / 128);                // 128 x 4
  // 2) gate + P (q converted inline from fp32)
  gemm_mfma<0><<<gg, 256, 0, stream>>>(q, nullptr, nullptr, gwb, nullptr, gb,
                                       nullptr, nullptr, Gbuf, Pb);
  // 3) D = P@A^T + R@Bm^T (bf16; overwrites dead fp32 r region)
  gemm_mfma<1><<<gg, 256, 0, stream>>>(nullptr, Pb, Rb, Ab, Bmb, nullptr,
                                       nullptr, Db, nullptr, nullptr);
  // 4) sequential recurrence
  seq_mfma<<<256, 1024, 0, stream>>>(Ab, Gbuf, Db, Sb);
  // 5) out = S@Wout^T + b
  gemm_mfma<2><<<gg, 256, 0, stream>>>(nullptr, Sb, nullptr, owb, nullptr, ob,
                                       out, nullptr, nullptr, nullptr);
}

// Round 3
// 367.488 us; speedup vs baseline: 1.0543x; 1.0543x over previous
//
#include <hip/hip_runtime.h>
#include <cmath>

#define DIM 512
#define NB 4
#define SEQ 4096

typedef __bf16 bf16;
typedef __bf16 bf16x8 __attribute__((ext_vector_type(8)));
typedef float  f32x4  __attribute__((ext_vector_type(4)));

__device__ __forceinline__ float fast_sig(float x) { return 1.f / (1.f + __expf(-x)); }
__device__ __forceinline__ float fast_tanh(float x) {
  float cx = fminf(fmaxf(x, -15.f), 15.f);
  float e = __expf(2.f * cx);
  return (e - 1.f) / (e + 1.f);
}
__device__ __forceinline__ bf16x8 ld8f(const float* p) {
  float4 u = *(const float4*)p, v = *(const float4*)(p + 4);
  return (bf16x8){(bf16)u.x, (bf16)u.y, (bf16)u.z, (bf16)u.w,
                  (bf16)v.x, (bf16)v.y, (bf16)v.z, (bf16)v.w};
}

// ---------------- r-scan: 3-pass exact chunked scan ----------------
constexpr int SC = 64, NSC = SEQ / SC;

__global__ __launch_bounds__(256) void scan_chunk(const float* __restrict__ K,
                                                  const float* __restrict__ V,
                                                  const float* __restrict__ decay,
                                                  float* __restrict__ R,
                                                  float* __restrict__ E) {
  int idx = blockIdx.x * 256 + threadIdx.x;     // NB*NSC*DIM = 131072
  int d = idx & (DIM - 1);
  int c = (idx >> 9) & (NSC - 1);
  int b = idx >> 15;
  float dec = decay[d >> 6];
  size_t base = ((size_t)b * SEQ + (size_t)c * SC) * DIM + d;
  float r = 0.f;
  #pragma unroll 4
  for (int i = 0; i < SC; ++i) {
    size_t o = base + (size_t)i * DIM;
    r = dec * r + K[o] * V[o];
    R[o] = r;
  }
  E[((size_t)b * NSC + c) * DIM + d] = r;
}

__global__ __launch_bounds__(256) void scan_carry(const float* __restrict__ E,
                                                  const float* __restrict__ decay,
                                                  float* __restrict__ P) {
  int idx = blockIdx.x * 256 + threadIdx.x;     // 2048
  int d = idx & (DIM - 1);
  int b = idx >> 9;
  float dec = decay[d >> 6];
  float lam = powf(dec, (float)SC);
  float pv = 0.f;
  for (int c = 0; c < NSC; ++c) {
    size_t o = ((size_t)b * NSC + c) * DIM + d;
    P[o] = pv;
    pv = E[o] + lam * pv;
  }
}

__global__ __launch_bounds__(256) void scan_fix_b(const float* __restrict__ decay,
                                                  const float* __restrict__ P,
                                                  const float* __restrict__ R,
                                                  bf16* __restrict__ Rb) {
  int idx = blockIdx.x * 256 + threadIdx.x;
  int d = idx & (DIM - 1);
  int c = (idx >> 9) & (NSC - 1);
  int b = idx >> 15;
  float pv = P[((size_t)b * NSC + c) * DIM + d];
  float dec = decay[d >> 6];
  size_t base = ((size_t)b * SEQ + (size_t)c * SC) * DIM + d;
  float wgt = dec;
  #pragma unroll 4
  for (int i = 0; i < SC; ++i) {
    size_t o = base + (size_t)i * DIM;
    Rb[o] = (bf16)(R[o] + wgt * pv);
    wgt *= dec;
  }
}

// ---------------- weight conversion: 4 x (512x512) fp32 -> bf16 ----------------
__global__ __launch_bounds__(256) void convert_w(const float* __restrict__ a,
                                                 const float* __restrict__ b,
                                                 const float* __restrict__ c,
                                                 const float* __restrict__ d,
                                                 bf16* __restrict__ o4) {
  int gid = blockIdx.x * 256 + threadIdx.x;     // 262144 threads, 4 elems each
  int m = gid >> 16;
  int off = (gid & 65535) << 2;
  const float* srcs[4] = {a, b, c, d};
  float4 v = *(const float4*)(srcs[m] + off);
  bf16* o = o4 + (size_t)m * 262144 + off;
  o[0] = (bf16)v.x; o[1] = (bf16)v.y; o[2] = (bf16)v.z; o[3] = (bf16)v.w;
}

// ---------------- MFMA GEMM, 128x128 tile: Out = X @ W^T ----------------
// MODE 0 (gate): X = q (fp32, converted in staging); g = sigmoid(z+gb);
//                Gout = g (bf16), Pout = (1-g)*q (bf16)
// MODE 1 (D):    z = Pb@Ab^T + Rb@Bmb^T (virtual K=1024); Bout = z (bf16)
// MODE 2 (out):  z = Sb@owb^T + ob;  Fout = z (fp32)
// 256 thr = 4 waves, each owns a 64x64 quadrant (4x4 grid of 16x16x32 MFMA).
// LDS rows padded to 72 bf16. Staging: each thread loads/stores 4 bf16x8 per
// matrix per k-tile (rows srow+32j), covering all 128 rows.
template <int MODE>
__global__ __launch_bounds__(256) void gemm_mfma(
    const float* __restrict__ Xf,
    const bf16* __restrict__ Xa, const bf16* __restrict__ Xc,
    const bf16* __restrict__ Wa, const bf16* __restrict__ Wb,
    const float* __restrict__ bias,
    float* __restrict__ Fout, bf16* __restrict__ Bout,
    bf16* __restrict__ Gout, bf16* __restrict__ Pout) {
  __shared__ __align__(16) bf16 Xs[128][72];
  __shared__ __align__(16) bf16 Ws[128][72];
  const int tid = threadIdx.x;
  const int wave = tid >> 6, lane = tid & 63;
  const int quad = lane >> 4, l16 = lane & 15;
  const int wm = wave & 1, wn = wave >> 1;
  const int m0 = blockIdx.x * 128, n0 = blockIdx.y * 128;
  const int srow = tid >> 3;            // 0..31 (rows srow+32j, j=0..3)
  const int scol = (tid & 7) * 8;       // 0..56

  const int KTOT = (MODE == 1) ? 2 * DIM : DIM;

  auto ldX = [&](int row, int k) -> bf16x8 {
    if constexpr (MODE == 0) {
      return ld8f(Xf + (size_t)row * DIM + k);
    } else if constexpr (MODE == 1) {
      const bf16* X = (k >= DIM) ? Xc : Xa;
      return *(const bf16x8*)(X + (size_t)row * DIM + (k & (DIM - 1)));
    } else {
      return *(const bf16x8*)(Xa + (size_t)row * DIM + k);
    }
  };
  auto ldW = [&](int row, int k) -> bf16x8 {
    const bf16* W = (MODE == 1 && k >= DIM) ? Wb : Wa;
    return *(const bf16x8*)(W + (size_t)row * DIM + (k & (DIM - 1)));
  };

  f32x4 acc[4][4] = {};
  bf16x8 px[4], pw[4];
  #pragma unroll
  for (int j = 0; j < 4; ++j) {
    px[j] = ldX(m0 + srow + 32 * j, scol);
    pw[j] = ldW(n0 + srow + 32 * j, scol);
  }

  for (int k0 = 0; k0 < KTOT; k0 += 64) {
    if (k0) __syncthreads();
    #pragma unroll
    for (int j = 0; j < 4; ++j) {
      *(bf16x8*)&Xs[srow + 32 * j][scol] = px[j];
      *(bf16x8*)&Ws[srow + 32 * j][scol] = pw[j];
    }
    if (k0 + 64 < KTOT) {
      #pragma unroll
      for (int j = 0; j < 4; ++j) {
        px[j] = ldX(m0 + srow + 32 * j, k0 + 64 + scol);
        pw[j] = ldW(n0 + srow + 32 * j, k0 + 64 + scol);
      }
    }
    __syncthreads();
    #pragma unroll
    for (int ks = 0; ks < 2; ++ks) {
      const int kk = ks * 32 + quad * 8;
      bf16x8 af[4], bfr[4];
      #pragma unroll
      for (int i = 0; i < 4; ++i) af[i]  = *(const bf16x8*)&Xs[wm * 64 + i * 16 + l16][kk];
      #pragma unroll
      for (int j = 0; j < 4; ++j) bfr[j] = *(const bf16x8*)&Ws[wn * 64 + j * 16 + l16][kk];
      #pragma unroll
      for (int i = 0; i < 4; ++i)
        #pragma unroll
        for (int j = 0; j < 4; ++j)
          acc[i][j] = __builtin_amdgcn_mfma_f32_16x16x32_bf16(af[i], bfr[j], acc[i][j], 0, 0, 0);
    }
  }

  #pragma unroll
  for (int i = 0; i < 4; ++i)
    #pragma unroll
    for (int j = 0; j < 4; ++j)
      #pragma unroll
      for (int r = 0; r < 4; ++r) {
        const int row = m0 + wm * 64 + i * 16 + quad * 4 + r;
        const int col = n0 + wn * 64 + j * 16 + l16;
        const size_t o = (size_t)row * DIM + col;
        const float z = acc[i][j][r];
        if constexpr (MODE == 0) {
          float g = fast_sig(z + bias[col]);
          Gout[o] = (bf16)g;
          Pout[o] = (bf16)((1.f - g) * Xf[o]);
        } else if constexpr (MODE == 1) {
          Bout[o] = (bf16)z;
        } else {
          Fout[o] = z + bias[col];
        }
      }
}

// ---------------- sequential core via MFMA ----------------
// 4096 streams (CC=4), 16 per WG -> 256 WGs (1 per CU). TT = 10 steps
// (WU=6 warmup + warm-start u0 = g_t0 * tanh(D_{t0-1}); residual ~3.6e-4
// after 6 steps, well under bf16 quantum of s; WU=6 validated by R1's pass
// at absmax 0.03125 == baseline).
// A is STEP-INVARIANT: k-tiles 0..NLT-1 live in LDS; NLT..15 stream from L2
// via a 4-slot register ring primed at step start.
// D/G loads are SAME-STEP (issued at step top, consumed in epilogue): the
// compiler already covers their latency with the MFMA section. Cross-step
// prefetch was tried (R1) and REGRESSED: compiler sinks the prefetch below
// the "memory"-clobbered barrier and re-issues it -> 2x D/G fetch traffic
// (FETCH 202->303 MB) with zero hiding. Do not reintroduce without asm-level
// register pinning.
// Interior WGs (62/64): t-range provably in-bounds -> unmasked D/G loads
// behind a WG-uniform branch (cuts cndmask/compare VALU from the hot path).
// The per-step barrier only needs LDS visibility, so we use raw
// "s_waitcnt lgkmcnt(0); s_barrier" — in-flight A loads (same data every
// step) and S stores legally cross the barrier.
constexpr int CC = 4, WU = 6, TT = CC + WU;
constexpr int NSTR = 16;
constexpr int USTR = 520;       // 1040 B row stride: 2-way bank alias (free)
constexpr int NLT = 3;          // LDS-resident A k-tiles per wave (96 KB/WG)

__global__ __launch_bounds__(1024, 4) void seq_mfma(const bf16* __restrict__ Ab,
                                                    const bf16* __restrict__ Gb,
                                                    const bf16* __restrict__ Db,
                                                    bf16* __restrict__ Sb) {
  __shared__ __align__(16) bf16 U[2][NSTR * USTR];        // 33,280 B
  __shared__ __align__(16) bf16 Alds[16 * NLT * 2 * 64 * 8]; // 98,304 B
  const int tid = threadIdx.x;
  const int wave = tid >> 6, lane = tid & 63;
  const int quad = lane >> 4, l16 = lane & 15;
  const int n0 = wave * 32;                      // 16 waves cover 512 cols
  const int b = blockIdx.x >> 6;                 // 64 WGs per batch
  const int cbase = (blockIdx.x & 63) * NSTR;    // 1024 chunks per batch
  const size_t base = (size_t)b * SEQ * DIM;
  // interior: all t and t+1 indices in-bounds for every step
  // (min t = cbase*CC - WU >= 0 iff cbase>0; max t+1 = (cbase+15)*CC+CC-1+
  //  (TT-1)-WU+1 <= 4095 iff cbase+NSTR < 1024)
  const bool interior = (cbase != 0) && (cbase + NSTR != 1024);

  const bf16* arow0 = Ab + (size_t)(n0 + l16) * DIM + quad * 8;
  const bf16* arow1 = arow0 + (size_t)16 * DIM;

  // stage this wave's first NLT A k-tiles into LDS (wave-private)
  bf16x8* Af = (bf16x8*)Alds;
  #pragma unroll
  for (int kt = 0; kt < NLT; ++kt) {
    Af[((wave * NLT + kt) * 2 + 0) * 64 + lane] = *(const bf16x8*)(arow0 + kt * 32);
    Af[((wave * NLT + kt) * 2 + 1) * 64 + lane] = *(const bf16x8*)(arow1 + kt * 32);
  }

  // warm-start: u = g_{t0} * tanh(D_{t0-1})  (zero where indices < 0)
  #pragma unroll
  for (int tn = 0; tn < 2; ++tn)
    #pragma unroll
    for (int r = 0; r < 4; ++r) {
      const int strm = quad * 4 + r;
      const int t0 = (cbase + strm) * CC - WU;
      const int col = n0 + tn * 16 + l16;
      float s0 = (t0 - 1 >= 0) ? fast_tanh((float)Db[base + (size_t)(t0 - 1) * DIM + col]) : 0.f;
      float g0 = (t0 >= 0) ? (float)Gb[base + (size_t)t0 * DIM + col] : 0.f;
      U[0][strm * USTR + col] = (bf16)(g0 * s0);
    }
  __syncthreads();

  int cur = 0;
  for (int p = 0; p < TT; ++p) {
    // prime streamed-A ring FIRST so the L2 loads issue earliest
    bf16x8 pb0[4], pb1[4];
    #pragma unroll
    for (int i = 0; i < 4; ++i) {
      pb0[i] = *(const bf16x8*)(arow0 + (NLT + i) * 32);
      pb1[i] = *(const bf16x8*)(arow1 + (NLT + i) * 32);
    }

    // same-step D/G loads (consumed in epilogue; MFMA section covers latency)
    float dv[2][4], gv[2][4];
    if (interior) {
      #pragma unroll
      for (int tn = 0; tn < 2; ++tn)
        #pragma unroll
        for (int r = 0; r < 4; ++r) {
          const int strm = quad * 4 + r;
          const int t = (cbase + strm) * CC + p - WU;
          const int col = n0 + tn * 16 + l16;
          dv[tn][r] = (float)Db[base + (size_t)t * DIM + col];
          gv[tn][r] = (float)Gb[base + (size_t)(t + 1) * DIM + col];
        }
    } else {
      #pragma unroll
      for (int tn = 0; tn < 2; ++tn)
        #pragma unroll
        for (int r = 0; r < 4; ++r) {
          const int strm = quad * 4 + r;
          const int t = (cbase + strm) * CC + p - WU;
          const int col = n0 + tn * 16 + l16;
          dv[tn][r] = (t >= 0) ? (float)Db[base + (size_t)t * DIM + col] : 0.f;
          gv[tn][r] = (t + 1 >= 0 && t + 1 < SEQ)
                          ? (float)Gb[base + (size_t)(t + 1) * DIM + col] : 0.f;
        }
    }

    f32x4 acc0 = {}, acc1 = {};
    const bf16* u0 = &U[cur][l16 * USTR + quad * 8];
    // LDS-resident tiles first (hides the ring's first-load latency)
    #pragma unroll
    for (int kt = 0; kt < NLT; ++kt) {
      bf16x8 av = *(const bf16x8*)(u0 + kt * 32);
      bf16x8 b0 = Af[((wave * NLT + kt) * 2 + 0) * 64 + lane];
      bf16x8 b1 = Af[((wave * NLT + kt) * 2 + 1) * 64 + lane];
      acc0 = __builtin_amdgcn_mfma_f32_16x16x32_bf16(av, b0, acc0, 0, 0, 0);
      acc1 = __builtin_amdgcn_mfma_f32_16x16x32_bf16(av, b1, acc1, 0, 0, 0);
    }
    // streamed tiles (L2), 4-slot ring
    #pragma unroll
    for (int kt = NLT; kt < 16; ++kt) {
      bf16x8 av = *(const bf16x8*)(u0 + kt * 32);
      const int slot = (kt - NLT) & 3;
      bf16x8 b0 = pb0[slot], b1 = pb1[slot];
      if (kt + 4 < 16) {
        pb0[slot] = *(const bf16x8*)(arow0 + (kt + 4) * 32);
        pb1[slot] = *(const bf16x8*)(arow1 + (kt + 4) * 32);
      }
      acc0 = __builtin_amdgcn_mfma_f32_16x16x32_bf16(av, b0, acc0, 0, 0, 0);
      acc1 = __builtin_amdgcn_mfma_f32_16x16x32_bf16(av, b1, acc1, 0, 0, 0);
    }

    const int nxt = cur ^ 1;
    #pragma unroll
    for (int tn = 0; tn < 2; ++tn)
      #pragma unroll
      for (int r = 0; r < 4; ++r) {
        const int strm = quad * 4 + r;
        const int t = (cbase + strm) * CC + p - WU;
        const int col = n0 + tn * 16 + l16;
        const float z = (tn ? acc1[r] : acc0[r]) + dv[tn][r];
        const float s = fast_tanh(z);
        if (p >= WU) Sb[base + (size_t)t * DIM + col] = (bf16)s;
        U[nxt][strm * USTR + col] = (bf16)(gv[tn][r] * s);
      }
    // LDS-only barrier: U writes must be visible; A loads / S stores may
    // legally remain in flight (A is constant, S is write-only).
    asm volatile("s_waitcnt lgkmcnt(0)\n\ts_barrier" ::: "memory");
    cur = nxt;
  }
}

// ---------------- launch ----------------
extern "C" void kernel_launch(void* const* d_in, const int* in_sizes, int n_in,
                              void* d_out, int out_size, void* d_ws, size_t ws_size,
                              hipStream_t stream) {
  const float* q     = (const float*)d_in[0];
  const float* k     = (const float*)d_in[1];
  const float* v     = (const float*)d_in[2];
  const float* A     = (const float*)d_in[3];
  const float* Bm    = (const float*)d_in[4];
  const float* gw    = (const float*)d_in[5];
  const float* gb    = (const float*)d_in[6];
  const float* ow    = (const float*)d_in[7];
  const float* ob    = (const float*)d_in[8];
  const float* decay = (const float*)d_in[9];
  float* out = (float*)d_out;

  const size_t NE = (size_t)NB * SEQ * DIM;       // 8,388,608
  char* w = (char*)d_ws;
  float* Rf  = (float*)w;  w += NE * 4;           // fp32 r (scan); reused as bf16 D
  float* Eb  = (float*)w;  w += (size_t)NB * NSC * DIM * 4;
  float* Pc  = (float*)w;  w += (size_t)NB * NSC * DIM * 4;
  bf16*  Gbuf= (bf16*)w;   w += NE * 2;
  bf16*  Pb  = (bf16*)w;   w += NE * 2;
  bf16*  Rb  = (bf16*)w;   w += NE * 2;           // bf16 r; reused as S
  bf16*  W4  = (bf16*)w;   w += 4 * 262144 * 2;   // ~83 MB total
  bf16 *gwb = W4, *Ab = W4 + 262144, *Bmb = W4 + 2 * 262144, *owb = W4 + 3 * 262144;
  bf16*  Db = (bf16*)Rf;                          // bf16 D overwrites dead fp32 r
  bf16*  Sb = Rb;

  // 1) exact chunked linear scan for r (fp32), emit bf16
  scan_chunk<<<512, 256, 0, stream>>>(k, v, decay, Rf, Eb);
  scan_carry<<<8, 256, 0, stream>>>(Eb, decay, Pc);
  scan_fix_b<<<512, 256, 0, stream>>>(decay, Pc, Rf, Rb);
  convert_w<<<1024, 256, 0, stream>>>(gw, A, Bm, ow, W4);

  dim3 gg(16384 / 128, DIM / 128);                // 128 x 4
  // 2) gate + P (q converted inline from fp32)
  gemm_mfma<0><<<gg, 256, 0, stream>>>(q, nullptr, nullptr, gwb, nullptr, gb,
                                       nullptr, nullptr, Gbuf, Pb);
  // 3) D = P@A^T + R@Bm^T (bf16; overwrites dead fp32 r region)
  gemm_mfma<1><<<gg, 256, 0, stream>>>(nullptr, Pb, Rb, Ab, Bmb, nullptr,
                                       nullptr, Db, nullptr, nullptr);
  // 4) sequential recurrence
  seq_mfma<<<256, 1024, 0, stream>>>(Ab, Gbuf, Db, Sb);
  // 5) out = S@Wout^T + b
  gemm_mfma<2><<<gg, 256, 0, stream>>>(nullptr, Sb, nullptr, owb, nullptr, ob,
                                       out, nullptr, nullptr, nullptr);
}

// Round 5
// 353.601 us; speedup vs baseline: 1.0957x; 1.0393x over previous
//
#include <hip/hip_runtime.h>
#include <cmath>

#define DIM 512
#define NB 4
#define SEQ 4096

typedef __bf16 bf16;
typedef __bf16 bf16x8 __attribute__((ext_vector_type(8)));
typedef float  f32x4  __attribute__((ext_vector_type(4)));

__device__ __forceinline__ float fast_sig(float x) { return 1.f / (1.f + __expf(-x)); }
__device__ __forceinline__ float fast_tanh(float x) {
  float cx = fminf(fmaxf(x, -15.f), 15.f);
  float e = __expf(2.f * cx);
  return (e - 1.f) / (e + 1.f);
}
__device__ __forceinline__ bf16x8 ld8f(const float* p) {
  float4 u = *(const float4*)p, v = *(const float4*)(p + 4);
  return (bf16x8){(bf16)u.x, (bf16)u.y, (bf16)u.z, (bf16)u.w,
                  (bf16)v.x, (bf16)v.y, (bf16)v.z, (bf16)v.w};
}

// ---------------- r-scan: 3-pass exact chunked scan ----------------
constexpr int SC = 64, NSC = SEQ / SC;

__global__ __launch_bounds__(256) void scan_chunk(const float* __restrict__ K,
                                                  const float* __restrict__ V,
                                                  const float* __restrict__ decay,
                                                  float* __restrict__ R,
                                                  float* __restrict__ E) {
  int idx = blockIdx.x * 256 + threadIdx.x;     // NB*NSC*DIM = 131072
  int d = idx & (DIM - 1);
  int c = (idx >> 9) & (NSC - 1);
  int b = idx >> 15;
  float dec = decay[d >> 6];
  size_t base = ((size_t)b * SEQ + (size_t)c * SC) * DIM + d;
  float r = 0.f;
  #pragma unroll 4
  for (int i = 0; i < SC; ++i) {
    size_t o = base + (size_t)i * DIM;
    r = dec * r + K[o] * V[o];
    R[o] = r;
  }
  E[((size_t)b * NSC + c) * DIM + d] = r;
}

// 32 blocks x 64 threads: spread the 2048 serial scan columns over 32 CUs
// (was 8x256 -> only 8 CUs active on a latency-bound 64-iteration loop).
__global__ __launch_bounds__(64) void scan_carry(const float* __restrict__ E,
                                                 const float* __restrict__ decay,
                                                 float* __restrict__ P) {
  int idx = blockIdx.x * 64 + threadIdx.x;      // 2048
  int d = idx & (DIM - 1);
  int b = idx >> 9;
  float dec = decay[d >> 6];
  float lam = powf(dec, (float)SC);
  float pv = 0.f;
  for (int c = 0; c < NSC; ++c) {
    size_t o = ((size_t)b * NSC + c) * DIM + d;
    P[o] = pv;
    pv = E[o] + lam * pv;
  }
}

__global__ __launch_bounds__(256) void scan_fix_b(const float* __restrict__ decay,
                                                  const float* __restrict__ P,
                                                  const float* __restrict__ R,
                                                  bf16* __restrict__ Rb) {
  int idx = blockIdx.x * 256 + threadIdx.x;
  int d = idx & (DIM - 1);
  int c = (idx >> 9) & (NSC - 1);
  int b = idx >> 15;
  float pv = P[((size_t)b * NSC + c) * DIM + d];
  float dec = decay[d >> 6];
  size_t base = ((size_t)b * SEQ + (size_t)c * SC) * DIM + d;
  float wgt = dec;
  #pragma unroll 4
  for (int i = 0; i < SC; ++i) {
    size_t o = base + (size_t)i * DIM;
    Rb[o] = (bf16)(R[o] + wgt * pv);
    wgt *= dec;
  }
}

// ---------------- weight conversion: 4 x (512x512) fp32 -> bf16 ----------------
__global__ __launch_bounds__(256) void convert_w(const float* __restrict__ a,
                                                 const float* __restrict__ b,
                                                 const float* __restrict__ c,
                                                 const float* __restrict__ d,
                                                 bf16* __restrict__ o4) {
  int gid = blockIdx.x * 256 + threadIdx.x;     // 262144 threads, 4 elems each
  int m = gid >> 16;
  int off = (gid & 65535) << 2;
  const float* srcs[4] = {a, b, c, d};
  float4 v = *(const float4*)(srcs[m] + off);
  bf16* o = o4 + (size_t)m * 262144 + off;
  o[0] = (bf16)v.x; o[1] = (bf16)v.y; o[2] = (bf16)v.z; o[3] = (bf16)v.w;
}

// ---------------- MFMA GEMM, 128x128 tile: Out = X @ W^T ----------------
// MODE 0 (gate): X = q (fp32, converted in staging); g = sigmoid(z+gb);
//                Gout = g (bf16), Pout = (1-g)*q (bf16)
// MODE 1 (D):    z = Pb@Ab^T + Rb@Bmb^T (virtual K=1024); Bout = z (bf16)
// MODE 2 (out):  z = Sb@owb^T + ob;  Fout = z (fp32)
// 256 thr = 4 waves, each owns a 64x64 quadrant (4x4 grid of 16x16x32 MFMA).
// LDS rows padded to 72 bf16. Staging: each thread loads/stores 4 bf16x8 per
// matrix per k-tile (rows srow+32j), covering all 128 rows.
template <int MODE>
__global__ __launch_bounds__(256) void gemm_mfma(
    const float* __restrict__ Xf,
    const bf16* __restrict__ Xa, const bf16* __restrict__ Xc,
    const bf16* __restrict__ Wa, const bf16* __restrict__ Wb,
    const float* __restrict__ bias,
    float* __restrict__ Fout, bf16* __restrict__ Bout,
    bf16* __restrict__ Gout, bf16* __restrict__ Pout) {
  __shared__ __align__(16) bf16 Xs[128][72];
  __shared__ __align__(16) bf16 Ws[128][72];
  const int tid = threadIdx.x;
  const int wave = tid >> 6, lane = tid & 63;
  const int quad = lane >> 4, l16 = lane & 15;
  const int wm = wave & 1, wn = wave >> 1;
  const int m0 = blockIdx.x * 128, n0 = blockIdx.y * 128;
  const int srow = tid >> 3;            // 0..31 (rows srow+32j, j=0..3)
  const int scol = (tid & 7) * 8;       // 0..56

  const int KTOT = (MODE == 1) ? 2 * DIM : DIM;

  auto ldX = [&](int row, int k) -> bf16x8 {
    if constexpr (MODE == 0) {
      return ld8f(Xf + (size_t)row * DIM + k);
    } else if constexpr (MODE == 1) {
      const bf16* X = (k >= DIM) ? Xc : Xa;
      return *(const bf16x8*)(X + (size_t)row * DIM + (k & (DIM - 1)));
    } else {
      return *(const bf16x8*)(Xa + (size_t)row * DIM + k);
    }
  };
  auto ldW = [&](int row, int k) -> bf16x8 {
    const bf16* W = (MODE == 1 && k >= DIM) ? Wb : Wa;
    return *(const bf16x8*)(W + (size_t)row * DIM + (k & (DIM - 1)));
  };

  f32x4 acc[4][4] = {};
  bf16x8 px[4], pw[4];
  #pragma unroll
  for (int j = 0; j < 4; ++j) {
    px[j] = ldX(m0 + srow + 32 * j, scol);
    pw[j] = ldW(n0 + srow + 32 * j, scol);
  }

  for (int k0 = 0; k0 < KTOT; k0 += 64) {
    if (k0) __syncthreads();
    #pragma unroll
    for (int j = 0; j < 4; ++j) {
      *(bf16x8*)&Xs[srow + 32 * j][scol] = px[j];
      *(bf16x8*)&Ws[srow + 32 * j][scol] = pw[j];
    }
    if (k0 + 64 < KTOT) {
      #pragma unroll
      for (int j = 0; j < 4; ++j) {
        px[j] = ldX(m0 + srow + 32 * j, k0 + 64 + scol);
        pw[j] = ldW(n0 + srow + 32 * j, k0 + 64 + scol);
      }
    }
    __syncthreads();
    #pragma unroll
    for (int ks = 0; ks < 2; ++ks) {
      const int kk = ks * 32 + quad * 8;
      bf16x8 af[4], bfr[4];
      #pragma unroll
      for (int i = 0; i < 4; ++i) af[i]  = *(const bf16x8*)&Xs[wm * 64 + i * 16 + l16][kk];
      #pragma unroll
      for (int j = 0; j < 4; ++j) bfr[j] = *(const bf16x8*)&Ws[wn * 64 + j * 16 + l16][kk];
      #pragma unroll
      for (int i = 0; i < 4; ++i)
        #pragma unroll
        for (int j = 0; j < 4; ++j)
          acc[i][j] = __builtin_amdgcn_mfma_f32_16x16x32_bf16(af[i], bfr[j], acc[i][j], 0, 0, 0);
    }
  }

  #pragma unroll
  for (int i = 0; i < 4; ++i)
    #pragma unroll
    for (int j = 0; j < 4; ++j)
      #pragma unroll
      for (int r = 0; r < 4; ++r) {
        const int row = m0 + wm * 64 + i * 16 + quad * 4 + r;
        const int col = n0 + wn * 64 + j * 16 + l16;
        const size_t o = (size_t)row * DIM + col;
        const float z = acc[i][j][r];
        if constexpr (MODE == 0) {
          float g = fast_sig(z + bias[col]);
          Gout[o] = (bf16)g;
          Pout[o] = (bf16)((1.f - g) * Xf[o]);
        } else if constexpr (MODE == 1) {
          Bout[o] = (bf16)z;
        } else {
          Fout[o] = z + bias[col];
        }
      }
}

// ---------------- sequential core via MFMA ----------------
// 4096 streams (CC=4), 16 per WG -> 256 WGs (1 per CU). TT = 10 steps
// (WU=6 warmup + warm-start u0 = g_t0 * tanh(D_{t0-1}); residual ~3.6e-4
// after 6 steps, under bf16 quantum of s; WU=6 validated by R1/R2 passes at
// absmax 0.03125 == baseline).
// STEP BODY IS THE MEASURED-OPTIMAL BASELINE FORM — do not restructure:
//  * R0 (reg-resident A tiles): compiler refused to keep them live, null.
//  * R1 (cross-step D/G prefetch): compiler sank loads below the barrier,
//    2x D/G fetch, -16% regression.
//  * R2 (WG-uniform unmasked-load branch): broke load/MFMA interleave,
//    per-step 10.5 -> 12.2 us regression.
// A is STEP-INVARIANT: k-tiles 0..NLT-1 live in LDS; NLT..15 stream from L2
// via a 4-slot register ring primed at step start. D/G loads are SAME-STEP,
// masked per-lane (compiler interleaves them with the MFMA section).
// The per-step barrier only needs LDS visibility, so we use raw
// "s_waitcnt lgkmcnt(0); s_barrier" — in-flight A loads (same data every
// step) and S stores legally cross the barrier.
constexpr int CC = 4, WU = 6, TT = CC + WU;
constexpr int NSTR = 16;
constexpr int USTR = 520;       // 1040 B row stride: 2-way bank alias (free)
constexpr int NLT = 3;          // LDS-resident A k-tiles per wave (96 KB/WG)

__global__ __launch_bounds__(1024, 4) void seq_mfma(const bf16* __restrict__ Ab,
                                                    const bf16* __restrict__ Gb,
                                                    const bf16* __restrict__ Db,
                                                    bf16* __restrict__ Sb) {
  __shared__ __align__(16) bf16 U[2][NSTR * USTR];        // 33,280 B
  __shared__ __align__(16) bf16 Alds[16 * NLT * 2 * 64 * 8]; // 98,304 B
  const int tid = threadIdx.x;
  const int wave = tid >> 6, lane = tid & 63;
  const int quad = lane >> 4, l16 = lane & 15;
  const int n0 = wave * 32;                      // 16 waves cover 512 cols
  const int b = blockIdx.x >> 6;                 // 64 WGs per batch
  const int cbase = (blockIdx.x & 63) * NSTR;    // 1024 chunks per batch
  const size_t base = (size_t)b * SEQ * DIM;

  const bf16* arow0 = Ab + (size_t)(n0 + l16) * DIM + quad * 8;
  const bf16* arow1 = arow0 + (size_t)16 * DIM;

  // stage this wave's first NLT A k-tiles into LDS (wave-private)
  bf16x8* Af = (bf16x8*)Alds;
  #pragma unroll
  for (int kt = 0; kt < NLT; ++kt) {
    Af[((wave * NLT + kt) * 2 + 0) * 64 + lane] = *(const bf16x8*)(arow0 + kt * 32);
    Af[((wave * NLT + kt) * 2 + 1) * 64 + lane] = *(const bf16x8*)(arow1 + kt * 32);
  }

  // warm-start: u = g_{t0} * tanh(D_{t0-1})  (zero where indices < 0)
  #pragma unroll
  for (int tn = 0; tn < 2; ++tn)
    #pragma unroll
    for (int r = 0; r < 4; ++r) {
      const int strm = quad * 4 + r;
      const int t0 = (cbase + strm) * CC - WU;
      const int col = n0 + tn * 16 + l16;
      float s0 = (t0 - 1 >= 0) ? fast_tanh((float)Db[base + (size_t)(t0 - 1) * DIM + col]) : 0.f;
      float g0 = (t0 >= 0) ? (float)Gb[base + (size_t)t0 * DIM + col] : 0.f;
      U[0][strm * USTR + col] = (bf16)(g0 * s0);
    }
  __syncthreads();

  int cur = 0;
  for (int p = 0; p < TT; ++p) {
    // prime streamed-A ring FIRST so the L2 loads issue earliest
    bf16x8 pb0[4], pb1[4];
    #pragma unroll
    for (int i = 0; i < 4; ++i) {
      pb0[i] = *(const bf16x8*)(arow0 + (NLT + i) * 32);
      pb1[i] = *(const bf16x8*)(arow1 + (NLT + i) * 32);
    }

    // hoist D/G loads for this step (consumed only in epilogue)
    float dv[2][4], gv[2][4];
    #pragma unroll
    for (int tn = 0; tn < 2; ++tn)
      #pragma unroll
      for (int r = 0; r < 4; ++r) {
        const int strm = quad * 4 + r;
        const int t = (cbase + strm) * CC + p - WU;
        const int col = n0 + tn * 16 + l16;
        dv[tn][r] = (t >= 0) ? (float)Db[base + (size_t)t * DIM + col] : 0.f;
        gv[tn][r] = (t + 1 >= 0 && t + 1 < SEQ)
                        ? (float)Gb[base + (size_t)(t + 1) * DIM + col] : 0.f;
      }

    f32x4 acc0 = {}, acc1 = {};
    const bf16* u0 = &U[cur][l16 * USTR + quad * 8];
    // LDS-resident tiles first (hides the ring's first-load latency)
    #pragma unroll
    for (int kt = 0; kt < NLT; ++kt) {
      bf16x8 av = *(const bf16x8*)(u0 + kt * 32);
      bf16x8 b0 = Af[((wave * NLT + kt) * 2 + 0) * 64 + lane];
      bf16x8 b1 = Af[((wave * NLT + kt) * 2 + 1) * 64 + lane];
      acc0 = __builtin_amdgcn_mfma_f32_16x16x32_bf16(av, b0, acc0, 0, 0, 0);
      acc1 = __builtin_amdgcn_mfma_f32_16x16x32_bf16(av, b1, acc1, 0, 0, 0);
    }
    #pragma unroll
    for (int kt = NLT; kt < 16; ++kt) {
      bf16x8 av = *(const bf16x8*)(u0 + kt * 32);
      const int slot = (kt - NLT) & 3;
      bf16x8 b0 = pb0[slot], b1 = pb1[slot];
      if (kt + 4 < 16) {
        pb0[slot] = *(const bf16x8*)(arow0 + (kt + 4) * 32);
        pb1[slot] = *(const bf16x8*)(arow1 + (kt + 4) * 32);
      }
      acc0 = __builtin_amdgcn_mfma_f32_16x16x32_bf16(av, b0, acc0, 0, 0, 0);
      acc1 = __builtin_amdgcn_mfma_f32_16x16x32_bf16(av, b1, acc1, 0, 0, 0);
    }

    const int nxt = cur ^ 1;
    #pragma unroll
    for (int tn = 0; tn < 2; ++tn)
      #pragma unroll
      for (int r = 0; r < 4; ++r) {
        const int strm = quad * 4 + r;
        const int t = (cbase + strm) * CC + p - WU;
        const int col = n0 + tn * 16 + l16;
        const float z = (tn ? acc1[r] : acc0[r]) + dv[tn][r];
        const float s = fast_tanh(z);
        if (p >= WU) Sb[base + (size_t)t * DIM + col] = (bf16)s;
        U[nxt][strm * USTR + col] = (bf16)(gv[tn][r] * s);
      }
    // LDS-only barrier: U writes must be visible; A loads / S stores may
    // legally remain in flight (A is constant, S is write-only).
    asm volatile("s_waitcnt lgkmcnt(0)\n\ts_barrier" ::: "memory");
    cur = nxt;
  }
}

// ---------------- launch ----------------
extern "C" void kernel_launch(void* const* d_in, const int* in_sizes, int n_in,
                              void* d_out, int out_size, void* d_ws, size_t ws_size,
                              hipStream_t stream) {
  const float* q     = (const float*)d_in[0];
  const float* k     = (const float*)d_in[1];
  const float* v     = (const float*)d_in[2];
  const float* A     = (const float*)d_in[3];
  const float* Bm    = (const float*)d_in[4];
  const float* gw    = (const float*)d_in[5];
  const float* gb    = (const float*)d_in[6];
  const float* ow    = (const float*)d_in[7];
  const float* ob    = (const float*)d_in[8];
  const float* decay = (const float*)d_in[9];
  float* out = (float*)d_out;

  const size_t NE = (size_t)NB * SEQ * DIM;       // 8,388,608
  char* w = (char*)d_ws;
  float* Rf  = (float*)w;  w += NE * 4;           // fp32 r (scan); reused as bf16 D
  float* Eb  = (float*)w;  w += (size_t)NB * NSC * DIM * 4;
  float* Pc  = (float*)w;  w += (size_t)NB * NSC * DIM * 4;
  bf16*  Gbuf= (bf16*)w;   w += NE * 2;
  bf16*  Pb  = (bf16*)w;   w += NE * 2;
  bf16*  Rb  = (bf16*)w;   w += NE * 2;           // bf16 r; reused as S
  bf16*  W4  = (bf16*)w;   w += 4 * 262144 * 2;   // ~83 MB total
  bf16 *gwb = W4, *Ab = W4 + 262144, *Bmb = W4 + 2 * 262144, *owb = W4 + 3 * 262144;
  bf16*  Db = (bf16*)Rf;                          // bf16 D overwrites dead fp32 r
  bf16*  Sb = Rb;

  // 1) exact chunked linear scan for r (fp32), emit bf16
  scan_chunk<<<512, 256, 0, stream>>>(k, v, decay, Rf, Eb);
  scan_carry<<<32, 64, 0, stream>>>(Eb, decay, Pc);
  scan_fix_b<<<512, 256, 0, stream>>>(decay, Pc, Rf, Rb);
  convert_w<<<1024, 256, 0, stream>>>(gw, A, Bm, ow, W4);

  dim3 gg(16384 / 128, DIM / 128);                // 128 x 4
  // 2) gate + P (q converted inline from fp32)
  gemm_mfma<0><<<gg, 256, 0, stream>>>(q, nullptr, nullptr, gwb, nullptr, gb,
                                       nullptr, nullptr, Gbuf, Pb);
  // 3) D = P@A^T + R@Bm^T (bf16; overwrites dead fp32 r region)
  gemm_mfma<1><<<gg, 256, 0, stream>>>(nullptr, Pb, Rb, Ab, Bmb, nullptr,
                                       nullptr, Db, nullptr, nullptr);
  // 4) sequential recurrence
  seq_mfma<<<256, 1024, 0, stream>>>(Ab, Gbuf, Db, Sb);
  // 5) out = S@Wout^T + b
  gemm_mfma<2><<<gg, 256, 0, stream>>>(nullptr, Sb, nullptr, owb, nullptr, ob,
                                       out, nullptr, nullptr, nullptr);
}

// Round 6
// 350.579 us; speedup vs baseline: 1.1051x; 1.0086x over previous
//
#include <hip/hip_runtime.h>
#include <cmath>

#define DIM 512
#define NB 4
#define SEQ 4096

typedef __bf16 bf16;
typedef __bf16 bf16x8 __attribute__((ext_vector_type(8)));
typedef float  f32x4  __attribute__((ext_vector_type(4)));

__device__ __forceinline__ float fast_sig(float x) { return 1.f / (1.f + __expf(-x)); }
__device__ __forceinline__ float fast_tanh(float x) {
  float cx = fminf(fmaxf(x, -15.f), 15.f);
  float e = __expf(2.f * cx);
  return (e - 1.f) / (e + 1.f);
}
__device__ __forceinline__ bf16x8 ld8f(const float* p) {
  float4 u = *(const float4*)p, v = *(const float4*)(p + 4);
  return (bf16x8){(bf16)u.x, (bf16)u.y, (bf16)u.z, (bf16)u.w,
                  (bf16)v.x, (bf16)v.y, (bf16)v.z, (bf16)v.w};
}

// ---------------- r-scan: 3-pass exact chunked scan ----------------
constexpr int SC = 64, NSC = SEQ / SC;

__global__ __launch_bounds__(256) void scan_chunk(const float* __restrict__ K,
                                                  const float* __restrict__ V,
                                                  const float* __restrict__ decay,
                                                  float* __restrict__ R,
                                                  float* __restrict__ E) {
  int idx = blockIdx.x * 256 + threadIdx.x;     // NB*NSC*DIM = 131072
  int d = idx & (DIM - 1);
  int c = (idx >> 9) & (NSC - 1);
  int b = idx >> 15;
  float dec = decay[d >> 6];
  size_t base = ((size_t)b * SEQ + (size_t)c * SC) * DIM + d;
  float r = 0.f;
  #pragma unroll 4
  for (int i = 0; i < SC; ++i) {
    size_t o = base + (size_t)i * DIM;
    r = dec * r + K[o] * V[o];
    R[o] = r;
  }
  E[((size_t)b * NSC + c) * DIM + d] = r;
}

// 32 blocks x 64 threads: spread the 2048 serial scan columns over 32 CUs
// (was 8x256 -> only 8 CUs active on a latency-bound 64-iteration loop).
__global__ __launch_bounds__(64) void scan_carry(const float* __restrict__ E,
                                                 const float* __restrict__ decay,
                                                 float* __restrict__ P) {
  int idx = blockIdx.x * 64 + threadIdx.x;      // 2048
  int d = idx & (DIM - 1);
  int b = idx >> 9;
  float dec = decay[d >> 6];
  float lam = powf(dec, (float)SC);
  float pv = 0.f;
  for (int c = 0; c < NSC; ++c) {
    size_t o = ((size_t)b * NSC + c) * DIM + d;
    P[o] = pv;
    pv = E[o] + lam * pv;
  }
}

__global__ __launch_bounds__(256) void scan_fix_b(const float* __restrict__ decay,
                                                  const float* __restrict__ P,
                                                  const float* __restrict__ R,
                                                  bf16* __restrict__ Rb) {
  int idx = blockIdx.x * 256 + threadIdx.x;
  int d = idx & (DIM - 1);
  int c = (idx >> 9) & (NSC - 1);
  int b = idx >> 15;
  float pv = P[((size_t)b * NSC + c) * DIM + d];
  float dec = decay[d >> 6];
  size_t base = ((size_t)b * SEQ + (size_t)c * SC) * DIM + d;
  float wgt = dec;
  #pragma unroll 4
  for (int i = 0; i < SC; ++i) {
    size_t o = base + (size_t)i * DIM;
    Rb[o] = (bf16)(R[o] + wgt * pv);
    wgt *= dec;
  }
}

// ---------------- weight conversion: 4 x (512x512) fp32 -> bf16 ----------------
__global__ __launch_bounds__(256) void convert_w(const float* __restrict__ a,
                                                 const float* __restrict__ b,
                                                 const float* __restrict__ c,
                                                 const float* __restrict__ d,
                                                 bf16* __restrict__ o4) {
  int gid = blockIdx.x * 256 + threadIdx.x;     // 262144 threads, 4 elems each
  int m = gid >> 16;
  int off = (gid & 65535) << 2;
  const float* srcs[4] = {a, b, c, d};
  float4 v = *(const float4*)(srcs[m] + off);
  bf16* o = o4 + (size_t)m * 262144 + off;
  o[0] = (bf16)v.x; o[1] = (bf16)v.y; o[2] = (bf16)v.z; o[3] = (bf16)v.w;
}

// ---------------- MFMA GEMM, 128x128 tile: Out = X @ W^T ----------------
// MODE 0 (gate): X = q (fp32, converted in staging); g = sigmoid(z+gb);
//                Gout = g (bf16), Pout = (1-g)*q (bf16)
// MODE 1 (D):    z = Pb@Ab^T + Rb@Bmb^T (virtual K=1024); Bout = z (bf16)
// MODE 2 (out):  z = Sb@owb^T + ob;  Fout = z (fp32)
// 256 thr = 4 waves, each owns a 64x64 quadrant (4x4 grid of 16x16x32 MFMA).
// LDS rows padded to 72 bf16. Staging: each thread loads/stores 4 bf16x8 per
// matrix per k-tile (rows srow+32j), covering all 128 rows.
template <int MODE>
__global__ __launch_bounds__(256) void gemm_mfma(
    const float* __restrict__ Xf,
    const bf16* __restrict__ Xa, const bf16* __restrict__ Xc,
    const bf16* __restrict__ Wa, const bf16* __restrict__ Wb,
    const float* __restrict__ bias,
    float* __restrict__ Fout, bf16* __restrict__ Bout,
    bf16* __restrict__ Gout, bf16* __restrict__ Pout) {
  __shared__ __align__(16) bf16 Xs[128][72];
  __shared__ __align__(16) bf16 Ws[128][72];
  const int tid = threadIdx.x;
  const int wave = tid >> 6, lane = tid & 63;
  const int quad = lane >> 4, l16 = lane & 15;
  const int wm = wave & 1, wn = wave >> 1;
  const int m0 = blockIdx.x * 128, n0 = blockIdx.y * 128;
  const int srow = tid >> 3;            // 0..31 (rows srow+32j, j=0..3)
  const int scol = (tid & 7) * 8;       // 0..56

  const int KTOT = (MODE == 1) ? 2 * DIM : DIM;

  auto ldX = [&](int row, int k) -> bf16x8 {
    if constexpr (MODE == 0) {
      return ld8f(Xf + (size_t)row * DIM + k);
    } else if constexpr (MODE == 1) {
      const bf16* X = (k >= DIM) ? Xc : Xa;
      return *(const bf16x8*)(X + (size_t)row * DIM + (k & (DIM - 1)));
    } else {
      return *(const bf16x8*)(Xa + (size_t)row * DIM + k);
    }
  };
  auto ldW = [&](int row, int k) -> bf16x8 {
    const bf16* W = (MODE == 1 && k >= DIM) ? Wb : Wa;
    return *(const bf16x8*)(W + (size_t)row * DIM + (k & (DIM - 1)));
  };

  f32x4 acc[4][4] = {};
  bf16x8 px[4], pw[4];
  #pragma unroll
  for (int j = 0; j < 4; ++j) {
    px[j] = ldX(m0 + srow + 32 * j, scol);
    pw[j] = ldW(n0 + srow + 32 * j, scol);
  }

  for (int k0 = 0; k0 < KTOT; k0 += 64) {
    if (k0) __syncthreads();
    #pragma unroll
    for (int j = 0; j < 4; ++j) {
      *(bf16x8*)&Xs[srow + 32 * j][scol] = px[j];
      *(bf16x8*)&Ws[srow + 32 * j][scol] = pw[j];
    }
    if (k0 + 64 < KTOT) {
      #pragma unroll
      for (int j = 0; j < 4; ++j) {
        px[j] = ldX(m0 + srow + 32 * j, k0 + 64 + scol);
        pw[j] = ldW(n0 + srow + 32 * j, k0 + 64 + scol);
      }
    }
    __syncthreads();
    #pragma unroll
    for (int ks = 0; ks < 2; ++ks) {
      const int kk = ks * 32 + quad * 8;
      bf16x8 af[4], bfr[4];
      #pragma unroll
      for (int i = 0; i < 4; ++i) af[i]  = *(const bf16x8*)&Xs[wm * 64 + i * 16 + l16][kk];
      #pragma unroll
      for (int j = 0; j < 4; ++j) bfr[j] = *(const bf16x8*)&Ws[wn * 64 + j * 16 + l16][kk];
      #pragma unroll
      for (int i = 0; i < 4; ++i)
        #pragma unroll
        for (int j = 0; j < 4; ++j)
          acc[i][j] = __builtin_amdgcn_mfma_f32_16x16x32_bf16(af[i], bfr[j], acc[i][j], 0, 0, 0);
    }
  }

  #pragma unroll
  for (int i = 0; i < 4; ++i)
    #pragma unroll
    for (int j = 0; j < 4; ++j)
      #pragma unroll
      for (int r = 0; r < 4; ++r) {
        const int row = m0 + wm * 64 + i * 16 + quad * 4 + r;
        const int col = n0 + wn * 64 + j * 16 + l16;
        const size_t o = (size_t)row * DIM + col;
        const float z = acc[i][j][r];
        if constexpr (MODE == 0) {
          float g = fast_sig(z + bias[col]);
          Gout[o] = (bf16)g;
          Pout[o] = (bf16)((1.f - g) * Xf[o]);
        } else if constexpr (MODE == 1) {
          Bout[o] = (bf16)z;
        } else {
          Fout[o] = z + bias[col];
        }
      }
}

// ---------------- sequential core via MFMA ----------------
// 4096 streams (CC=4), 16 per WG -> 256 WGs (1 per CU). TT = 9 steps
// (WU=5 warmup + warm-start u0 = g_t0 * tanh(D_{t0-1}); initial s-err ~0.12,
// rms contracts <=0.38/step -> residual ~9.5e-4 after 5 steps, still ~4x
// under the bf16 quantum of s (~3.9e-3). WU=6 validated by R1/R2/R5 passes
// at absmax 0.03125 == baseline; WU=5 is this round's single isolated change
// so any absmax movement attributes to it.)
// Cost model (validated R5): seq = ~4 us prologue + TT x ~10.7 us/step.
// Step count is the only lever monotone in BOTH latency (TT steps) and HBM
// traffic (D/G bytes scale as TT/CC). CC=2-style restructures REJECTED:
// redundant D/G reads scale (CC+WU)/CC -> 134 MB at CC=2/TT=8 vs 84 now,
// and the scattered-32B D/G pattern would become the binding constraint.
// STEP BODY IS THE MEASURED-OPTIMAL BASELINE FORM — do not restructure:
//  * R0 (reg-resident A tiles): compiler refused to keep them live, null.
//  * R1 (cross-step D/G prefetch): compiler sank loads below the barrier,
//    2x D/G fetch, -16% regression.
//  * R2 (WG-uniform unmasked-load branch): broke load/MFMA interleave,
//    per-step 10.5 -> 12.2 us regression.
// A is STEP-INVARIANT: k-tiles 0..NLT-1 live in LDS; NLT..15 stream from L2
// via a 4-slot register ring primed at step start. D/G loads are SAME-STEP,
// masked per-lane (compiler interleaves them with the MFMA section).
// The per-step barrier only needs LDS visibility, so we use raw
// "s_waitcnt lgkmcnt(0); s_barrier" — in-flight A loads (same data every
// step) and S stores legally cross the barrier.
constexpr int CC = 4, WU = 5, TT = CC + WU;
constexpr int NSTR = 16;
constexpr int USTR = 520;       // 1040 B row stride: 2-way bank alias (free)
constexpr int NLT = 3;          // LDS-resident A k-tiles per wave (96 KB/WG)

__global__ __launch_bounds__(1024, 4) void seq_mfma(const bf16* __restrict__ Ab,
                                                    const bf16* __restrict__ Gb,
                                                    const bf16* __restrict__ Db,
                                                    bf16* __restrict__ Sb) {
  __shared__ __align__(16) bf16 U[2][NSTR * USTR];        // 33,280 B
  __shared__ __align__(16) bf16 Alds[16 * NLT * 2 * 64 * 8]; // 98,304 B
  const int tid = threadIdx.x;
  const int wave = tid >> 6, lane = tid & 63;
  const int quad = lane >> 4, l16 = lane & 15;
  const int n0 = wave * 32;                      // 16 waves cover 512 cols
  const int b = blockIdx.x >> 6;                 // 64 WGs per batch
  const int cbase = (blockIdx.x & 63) * NSTR;    // 1024 chunks per batch
  const size_t base = (size_t)b * SEQ * DIM;

  const bf16* arow0 = Ab + (size_t)(n0 + l16) * DIM + quad * 8;
  const bf16* arow1 = arow0 + (size_t)16 * DIM;

  // stage this wave's first NLT A k-tiles into LDS (wave-private)
  bf16x8* Af = (bf16x8*)Alds;
  #pragma unroll
  for (int kt = 0; kt < NLT; ++kt) {
    Af[((wave * NLT + kt) * 2 + 0) * 64 + lane] = *(const bf16x8*)(arow0 + kt * 32);
    Af[((wave * NLT + kt) * 2 + 1) * 64 + lane] = *(const bf16x8*)(arow1 + kt * 32);
  }

  // warm-start: u = g_{t0} * tanh(D_{t0-1})  (zero where indices < 0)
  #pragma unroll
  for (int tn = 0; tn < 2; ++tn)
    #pragma unroll
    for (int r = 0; r < 4; ++r) {
      const int strm = quad * 4 + r;
      const int t0 = (cbase + strm) * CC - WU;
      const int col = n0 + tn * 16 + l16;
      float s0 = (t0 - 1 >= 0) ? fast_tanh((float)Db[base + (size_t)(t0 - 1) * DIM + col]) : 0.f;
      float g0 = (t0 >= 0) ? (float)Gb[base + (size_t)t0 * DIM + col] : 0.f;
      U[0][strm * USTR + col] = (bf16)(g0 * s0);
    }
  __syncthreads();

  int cur = 0;
  for (int p = 0; p < TT; ++p) {
    // prime streamed-A ring FIRST so the L2 loads issue earliest
    bf16x8 pb0[4], pb1[4];
    #pragma unroll
    for (int i = 0; i < 4; ++i) {
      pb0[i] = *(const bf16x8*)(arow0 + (NLT + i) * 32);
      pb1[i] = *(const bf16x8*)(arow1 + (NLT + i) * 32);
    }

    // hoist D/G loads for this step (consumed only in epilogue)
    float dv[2][4], gv[2][4];
    #pragma unroll
    for (int tn = 0; tn < 2; ++tn)
      #pragma unroll
      for (int r = 0; r < 4; ++r) {
        const int strm = quad * 4 + r;
        const int t = (cbase + strm) * CC + p - WU;
        const int col = n0 + tn * 16 + l16;
        dv[tn][r] = (t >= 0) ? (float)Db[base + (size_t)t * DIM + col] : 0.f;
        gv[tn][r] = (t + 1 >= 0 && t + 1 < SEQ)
                        ? (float)Gb[base + (size_t)(t + 1) * DIM + col] : 0.f;
      }

    f32x4 acc0 = {}, acc1 = {};
    const bf16* u0 = &U[cur][l16 * USTR + quad * 8];
    // LDS-resident tiles first (hides the ring's first-load latency)
    #pragma unroll
    for (int kt = 0; kt < NLT; ++kt) {
      bf16x8 av = *(const bf16x8*)(u0 + kt * 32);
      bf16x8 b0 = Af[((wave * NLT + kt) * 2 + 0) * 64 + lane];
      bf16x8 b1 = Af[((wave * NLT + kt) * 2 + 1) * 64 + lane];
      acc0 = __builtin_amdgcn_mfma_f32_16x16x32_bf16(av, b0, acc0, 0, 0, 0);
      acc1 = __builtin_amdgcn_mfma_f32_16x16x32_bf16(av, b1, acc1, 0, 0, 0);
    }
    #pragma unroll
    for (int kt = NLT; kt < 16; ++kt) {
      bf16x8 av = *(const bf16x8*)(u0 + kt * 32);
      const int slot = (kt - NLT) & 3;
      bf16x8 b0 = pb0[slot], b1 = pb1[slot];
      if (kt + 4 < 16) {
        pb0[slot] = *(const bf16x8*)(arow0 + (kt + 4) * 32);
        pb1[slot] = *(const bf16x8*)(arow1 + (kt + 4) * 32);
      }
      acc0 = __builtin_amdgcn_mfma_f32_16x16x32_bf16(av, b0, acc0, 0, 0, 0);
      acc1 = __builtin_amdgcn_mfma_f32_16x16x32_bf16(av, b1, acc1, 0, 0, 0);
    }

    const int nxt = cur ^ 1;
    #pragma unroll
    for (int tn = 0; tn < 2; ++tn)
      #pragma unroll
      for (int r = 0; r < 4; ++r) {
        const int strm = quad * 4 + r;
        const int t = (cbase + strm) * CC + p - WU;
        const int col = n0 + tn * 16 + l16;
        const float z = (tn ? acc1[r] : acc0[r]) + dv[tn][r];
        const float s = fast_tanh(z);
        if (p >= WU) Sb[base + (size_t)t * DIM + col] = (bf16)s;
        U[nxt][strm * USTR + col] = (bf16)(gv[tn][r] * s);
      }
    // LDS-only barrier: U writes must be visible; A loads / S stores may
    // legally remain in flight (A is constant, S is write-only).
    asm volatile("s_waitcnt lgkmcnt(0)\n\ts_barrier" ::: "memory");
    cur = nxt;
  }
}

// ---------------- launch ----------------
extern "C" void kernel_launch(void* const* d_in, const int* in_sizes, int n_in,
                              void* d_out, int out_size, void* d_ws, size_t ws_size,
                              hipStream_t stream) {
  const float* q     = (const float*)d_in[0];
  const float* k     = (const float*)d_in[1];
  const float* v     = (const float*)d_in[2];
  const float* A     = (const float*)d_in[3];
  const float* Bm    = (const float*)d_in[4];
  const float* gw    = (const float*)d_in[5];
  const float* gb    = (const float*)d_in[6];
  const float* ow    = (const float*)d_in[7];
  const float* ob    = (const float*)d_in[8];
  const float* decay = (const float*)d_in[9];
  float* out = (float*)d_out;

  const size_t NE = (size_t)NB * SEQ * DIM;       // 8,388,608
  char* w = (char*)d_ws;
  float* Rf  = (float*)w;  w += NE * 4;           // fp32 r (scan); reused as bf16 D
  float* Eb  = (float*)w;  w += (size_t)NB * NSC * DIM * 4;
  float* Pc  = (float*)w;  w += (size_t)NB * NSC * DIM * 4;
  bf16*  Gbuf= (bf16*)w;   w += NE * 2;
  bf16*  Pb  = (bf16*)w;   w += NE * 2;
  bf16*  Rb  = (bf16*)w;   w += NE * 2;           // bf16 r; reused as S
  bf16*  W4  = (bf16*)w;   w += 4 * 262144 * 2;   // ~83 MB total
  bf16 *gwb = W4, *Ab = W4 + 262144, *Bmb = W4 + 2 * 262144, *owb = W4 + 3 * 262144;
  bf16*  Db = (bf16*)Rf;                          // bf16 D overwrites dead fp32 r
  bf16*  Sb = Rb;

  // 1) exact chunked linear scan for r (fp32), emit bf16
  scan_chunk<<<512, 256, 0, stream>>>(k, v, decay, Rf, Eb);
  scan_carry<<<32, 64, 0, stream>>>(Eb, decay, Pc);
  scan_fix_b<<<512, 256, 0, stream>>>(decay, Pc, Rf, Rb);
  convert_w<<<1024, 256, 0, stream>>>(gw, A, Bm, ow, W4);

  dim3 gg(16384 / 128, DIM / 128);                // 128 x 4
  // 2) gate + P (q converted inline from fp32)
  gemm_mfma<0><<<gg, 256, 0, stream>>>(q, nullptr, nullptr, gwb, nullptr, gb,
                                       nullptr, nullptr, Gbuf, Pb);
  // 3) D = P@A^T + R@Bm^T (bf16; overwrites dead fp32 r region)
  gemm_mfma<1><<<gg, 256, 0, stream>>>(nullptr, Pb, Rb, Ab, Bmb, nullptr,
                                       nullptr, Db, nullptr, nullptr);
  // 4) sequential recurrence
  seq_mfma<<<256, 1024, 0, stream>>>(Ab, Gbuf, Db, Sb);
  // 5) out = S@Wout^T + b
  gemm_mfma<2><<<gg, 256, 0, stream>>>(nullptr, Sb, nullptr, owb, nullptr, ob,
                                       out, nullptr, nullptr, nullptr);
}